// Round 4
// baseline (337.318 us; speedup 1.0000x reference)
//
#include <hip/hip_runtime.h>
#include <cstddef>

#define BATCH 32
#define EMBD 1024
#define SCTX 1023   // cached positions
#define CTXF 1024   // full context after concat
#define HIDD 4096
#define VOC 65535
#define CH 32       // flash-attention context chunk
#define NCH 32      // CTXF / CH

// ---------------- embed: x[b] = emb[idx[b]] + pos[0] ----------------
__global__ void embed_kernel(const int* __restrict__ idx, const float* __restrict__ emb,
                             const float* __restrict__ pos, float* __restrict__ x) {
  int b = blockIdx.x, t = threadIdx.x;  // 32 blocks x 256
  const float4* er = (const float4*)(emb + (size_t)idx[b] * EMBD);
  const float4* pr = (const float4*)pos;
  float4 e = er[t], p = pr[t];
  ((float4*)(x + (size_t)b * EMBD))[t] = make_float4(e.x + p.x, e.y + p.y, e.z + p.z, e.w + p.w);
}

// ---------------- split-K skinny GEMM for QKV ----------------
__global__ void skgemm_qkv(const float* __restrict__ X,
                           const float* __restrict__ Wk, const float* __restrict__ Wv,
                           const float* __restrict__ Wq,
                           float* __restrict__ Pout, int chunk) {
  const float* __restrict__ W = (blockIdx.z == 0) ? Wk : (blockIdx.z == 1) ? Wv : Wq;
  int j = blockIdx.x * 256 + threadIdx.x;       // grid.x = 4
  int p = blockIdx.y;
  int nch = gridDim.y;
  float acc[BATCH];
#pragma unroll
  for (int b = 0; b < BATCH; ++b) acc[b] = 0.f;
  int i0 = p * chunk;
#pragma unroll 8
  for (int i = i0; i < i0 + chunk; ++i) {
    float w = W[(size_t)i * EMBD + j];
#pragma unroll
    for (int b = 0; b < BATCH; ++b) acc[b] = fmaf(X[b * EMBD + i], w, acc[b]);
  }
#pragma unroll
  for (int b = 0; b < BATCH; ++b)
    Pout[((size_t)(blockIdx.z * nch + p) * BATCH + b) * EMBD + j] = acc[b];
}

// float4 reduce for qkv: grid (32, 3)
__global__ void reduce_qkv4(const float* __restrict__ part, int P,
                            const float* __restrict__ bk, const float* __restrict__ bv,
                            const float* __restrict__ bq,
                            float* __restrict__ kout, float* __restrict__ vout,
                            float* __restrict__ qout) {
  int z = blockIdx.y;
  int m4 = blockIdx.x * 256 + threadIdx.x;      // < 8192
  float4 s = make_float4(0.f, 0.f, 0.f, 0.f);
  for (int p = 0; p < P; ++p) {
    float4 v = ((const float4*)part)[(size_t)(z * P + p) * (BATCH * EMBD / 4) + m4];
    s.x += v.x; s.y += v.y; s.z += v.z; s.w += v.w;
  }
  const float* bias = (z == 0) ? bk : (z == 1) ? bv : bq;
  float* out = (z == 0) ? kout : (z == 1) ? vout : qout;
  float4 bb = *(const float4*)(bias + ((m4 * 4) & (EMBD - 1)));
  s.x += bb.x; s.y += bb.y; s.z += bb.z; s.w += bb.w;
  ((float4*)out)[m4] = s;
}

template <int BB>
__global__ void skgemm(const float* __restrict__ X, const float* __restrict__ W,
                       float* __restrict__ Pout, int N, int K, int chunk) {
  int j = blockIdx.x * 256 + threadIdx.x;
  int p = blockIdx.y;
  float acc[BB];
#pragma unroll
  for (int b = 0; b < BB; ++b) acc[b] = 0.f;
  int i0 = p * chunk, i1 = i0 + chunk;
#pragma unroll 8
  for (int i = i0; i < i1; ++i) {
    float w = W[(size_t)i * N + j];
#pragma unroll
    for (int b = 0; b < BB; ++b) acc[b] = fmaf(X[b * K + i], w, acc[b]);
  }
#pragma unroll
  for (int b = 0; b < BB; ++b) Pout[((size_t)p * BB + b) * N + j] = acc[b];
}

// float4 reduce: out4[m4] = act( sum_p part4[p][m4] + bias4 )
__global__ void reduce_ep4(const float* __restrict__ part, int P,
                           const float* __restrict__ bias, float* __restrict__ out,
                           int total4, int mask, int act) {
  int m4 = blockIdx.x * 256 + threadIdx.x;
  if (m4 >= total4) return;
  float4 s = make_float4(0.f, 0.f, 0.f, 0.f);
  for (int p = 0; p < P; ++p) {
    float4 v = ((const float4*)part)[(size_t)p * total4 + m4];
    s.x += v.x; s.y += v.y; s.z += v.z; s.w += v.w;
  }
  if (bias) {
    float4 bb = *(const float4*)(bias + ((m4 * 4) & mask));
    s.x += bb.x; s.y += bb.y; s.z += bb.z; s.w += bb.w;
  }
  if (act == 1) {
    s.x = 0.5f * s.x * (1.f + erff(s.x * 0.70710678118654752f));
    s.y = 0.5f * s.y * (1.f + erff(s.y * 0.70710678118654752f));
    s.z = 0.5f * s.z * (1.f + erff(s.z * 0.70710678118654752f));
    s.w = 0.5f * s.w * (1.f + erff(s.w * 0.70710678118654752f));
  }
  ((float4*)out)[m4] = s;
}

// ---------------- flash attention ----------------
// grid (NCH, BATCH), 256 threads. Per block: CH rows of K and V, streamed once.
__global__ __launch_bounds__(256) void attnA(const float* __restrict__ q,
                                             const float* __restrict__ kcache,
                                             const float* __restrict__ knew,
                                             const float* __restrict__ vcache,
                                             const float* __restrict__ vnew,
                                             float* __restrict__ opart,
                                             float* __restrict__ ml) {
  int b = blockIdx.y, c = blockIdx.x;
  int wave = threadIdx.x >> 6, lane = threadIdx.x & 63;
  __shared__ float sc[CH], pexp[CH];
  const float* qb = q + (size_t)b * EMBD;
  float4 qf[4];
#pragma unroll
  for (int r = 0; r < 4; ++r) qf[r] = *(const float4*)(qb + r * 256 + lane * 4);
  int s0 = c * CH;
  // phase 1: CH scores (each wave: 8 rows via 2 groups of 4 concurrent)
#pragma unroll
  for (int g = 0; g < 2; ++g) {
    int sbase = s0 + wave * 8 + g * 4;
    const float* kr[4];
    float acc[4] = {0.f, 0.f, 0.f, 0.f};
#pragma unroll
    for (int it = 0; it < 4; ++it) {
      int s = sbase + it;
      kr[it] = (s < SCTX) ? (kcache + ((size_t)b * SCTX + s) * EMBD)
                          : (knew + (size_t)b * EMBD);
    }
#pragma unroll
    for (int r = 0; r < 4; ++r) {
#pragma unroll
      for (int it = 0; it < 4; ++it) {
        float4 kf = *(const float4*)(kr[it] + r * 256 + lane * 4);
        acc[it] += qf[r].x * kf.x + qf[r].y * kf.y + qf[r].z * kf.z + qf[r].w * kf.w;
      }
    }
#pragma unroll
    for (int it = 0; it < 4; ++it) {
      float a = acc[it];
#pragma unroll
      for (int m = 32; m > 0; m >>= 1) a += __shfl_xor(a, m, 64);
      if (lane == 0) sc[sbase - s0 + it] = a * 0.03125f;  // 1/sqrt(1024)
    }
  }
  __syncthreads();
  // phase 2: local max + exp
  float m = sc[0];
#pragma unroll
  for (int s = 1; s < CH; ++s) m = fmaxf(m, sc[s]);
  if (threadIdx.x < CH) pexp[threadIdx.x] = expf(sc[threadIdx.x] - m);
  __syncthreads();
  if (threadIdx.x == 0) {
    float l = 0.f;
#pragma unroll
    for (int s = 0; s < CH; ++s) l += pexp[s];
    ml[((size_t)c * BATCH + b) * 2] = m;
    ml[((size_t)c * BATCH + b) * 2 + 1] = l;
  }
  // phase 3: partial PV
  int t = threadIdx.x;
  float acc2[4] = {0.f, 0.f, 0.f, 0.f};
#pragma unroll 4
  for (int s = 0; s < CH; ++s) {
    float pr = pexp[s];
    const float* vrow = (s0 + s < SCTX) ? (vcache + ((size_t)b * SCTX + s0 + s) * EMBD)
                                        : (vnew + (size_t)b * EMBD);
#pragma unroll
    for (int r = 0; r < 4; ++r) acc2[r] = fmaf(pr, vrow[t + r * 256], acc2[r]);
  }
#pragma unroll
  for (int r = 0; r < 4; ++r)
    opart[((size_t)c * BATCH + b) * EMBD + t + r * 256] = acc2[r];
}

// grid (BATCH), 256 threads: combine NCH chunks
__global__ void attnB(const float* __restrict__ opart, const float* __restrict__ ml,
                      float* __restrict__ attn) {
  int b = blockIdx.x, t = threadIdx.x;
  float M = ml[(size_t)b * 2];
#pragma unroll
  for (int c = 1; c < NCH; ++c) M = fmaxf(M, ml[((size_t)c * BATCH + b) * 2]);
  float L = 0.f;
#pragma unroll
  for (int c = 0; c < NCH; ++c)
    L += expf(ml[((size_t)c * BATCH + b) * 2] - M) * ml[((size_t)c * BATCH + b) * 2 + 1];
  float inv = 1.f / L;
  float acc[4] = {0.f, 0.f, 0.f, 0.f};
  for (int c = 0; c < NCH; ++c) {
    float wc = expf(ml[((size_t)c * BATCH + b) * 2] - M);
#pragma unroll
    for (int r = 0; r < 4; ++r)
      acc[r] = fmaf(wc, opart[((size_t)c * BATCH + b) * EMBD + t + r * 256], acc[r]);
  }
#pragma unroll
  for (int r = 0; r < 4; ++r) attn[(size_t)b * EMBD + t + r * 256] = acc[r] * inv;
}

// ---------------- logits ----------------
// grid (128, 4), 256 threads. Block: 512 cols x 256-i K-chunk; X staged transposed in LDS.
__global__ __launch_bounds__(256) void logits_v3(const float* __restrict__ X,
                                                 const float* __restrict__ Wl,
                                                 float* __restrict__ part) {
  __shared__ float xt[256][BATCH];  // 32 KB
  int t = threadIdx.x;
  int p = blockIdx.y;
  int q0 = p * 256;
  for (int m = t; m < 256 * BATCH; m += 256) {
    int i = m >> 5, b = m & 31;
    xt[i][b] = X[b * EMBD + q0 + i];
  }
  __syncthreads();

  int jb = blockIdx.x * 512;
  int j0 = jb + t;
  int j1 = jb + 256 + t;
  bool v1 = (j1 < VOC);
  float acc0[BATCH], acc1[BATCH];
#pragma unroll
  for (int b = 0; b < BATCH; ++b) { acc0[b] = 0.f; acc1[b] = 0.f; }

  const float* wp = Wl + (size_t)q0 * VOC;
#pragma unroll 8
  for (int i = 0; i < 256; ++i) {
    float w0 = wp[(size_t)i * VOC + j0];
    float w1 = v1 ? wp[(size_t)i * VOC + j1] : 0.f;
#pragma unroll
    for (int b = 0; b < BATCH; ++b) {
      float xv = xt[i][b];
      acc0[b] = fmaf(xv, w0, acc0[b]);
      acc1[b] = fmaf(xv, w1, acc1[b]);
    }
  }
#pragma unroll
  for (int b = 0; b < BATCH; ++b) {
    part[((size_t)p * BATCH + b) * VOC + j0] = acc0[b];
    if (v1) part[((size_t)p * BATCH + b) * VOC + j1] = acc1[b];
  }
}

// float4 reduce with wrap-around bias indexing. grid 2048 x 256.
__global__ void logits_reduce4(const float* __restrict__ part, const float* __restrict__ bl,
                               float* __restrict__ out) {
  unsigned m4 = blockIdx.x * 256 + threadIdx.x;
  const unsigned N4 = (unsigned)BATCH * VOC / 4;  // 524280
  if (m4 >= N4) return;
  float4 s = make_float4(0.f, 0.f, 0.f, 0.f);
#pragma unroll
  for (int p = 0; p < 4; ++p) {
    float4 v = ((const float4*)part)[(size_t)p * N4 + m4];
    s.x += v.x; s.y += v.y; s.z += v.z; s.w += v.w;
  }
  unsigned e0 = m4 * 4u;
  unsigned j = e0 % (unsigned)VOC;
  unsigned j1 = j + 1 >= VOC ? j + 1 - VOC : j + 1;
  unsigned j2 = j + 2 >= VOC ? j + 2 - VOC : j + 2;
  unsigned j3 = j + 3 >= VOC ? j + 3 - VOC : j + 3;
  s.x += bl[j]; s.y += bl[j1]; s.z += bl[j2]; s.w += bl[j3];
  ((float4*)out)[m4] = s;
}

// fallback (small ws): split batch in halves, full K, direct write
__global__ void logits_splitb(const float* __restrict__ X, const float* __restrict__ Wl,
                              const float* __restrict__ bl, float* __restrict__ out) {
  int j = blockIdx.x * 256 + threadIdx.x;
  if (j >= VOC) return;
  int b0 = blockIdx.y * 16;
  float acc[16];
#pragma unroll
  for (int b = 0; b < 16; ++b) acc[b] = 0.f;
#pragma unroll 8
  for (int i = 0; i < EMBD; ++i) {
    float w = Wl[(size_t)i * VOC + j];
#pragma unroll
    for (int b = 0; b < 16; ++b) acc[b] = fmaf(X[(b0 + b) * EMBD + i], w, acc[b]);
  }
  float bb = bl[j];
#pragma unroll
  for (int b = 0; b < 16; ++b) out[(size_t)(b0 + b) * VOC + j] = acc[b] + bb;
}

extern "C" void kernel_launch(void* const* d_in, const int* in_sizes, int n_in,
                              void* d_out, int out_size, void* d_ws, size_t ws_size,
                              hipStream_t stream) {
  const int* idx = (const int*)d_in[0];
  const float* key_cache = (const float*)d_in[1];
  const float* value_cache = (const float*)d_in[2];
  const float* emb_table = (const float*)d_in[3];
  const float* pos_table = (const float*)d_in[4];
  const float* Wk = (const float*)d_in[5];
  const float* bk = (const float*)d_in[6];
  const float* Wv = (const float*)d_in[7];
  const float* bv = (const float*)d_in[8];
  const float* Wq = (const float*)d_in[9];
  const float* bq = (const float*)d_in[10];
  const float* W1 = (const float*)d_in[11];
  const float* b1 = (const float*)d_in[12];
  const float* W2 = (const float*)d_in[13];
  const float* b2 = (const float*)d_in[14];
  const float* Wl = (const float*)d_in[15];
  const float* bl = (const float*)d_in[16];
  float* out = (float*)d_out;

  float* ws = (float*)d_ws;
  float* x     = ws;              // 32768
  float* k     = ws + 32768;
  float* v     = ws + 65536;
  float* q     = ws + 98304;
  float* attn  = ws + 131072;
  float* h     = ws + 163840;     // 131072
  float* ffn   = ws + 294912;     // 32768
  float* opart = ws + 327680;     // NCH*32*1024 = 1048576
  float* ml    = ws + 1376256;    // NCH*32*2 = 2048
  float* part  = ws + 1378304;    // up to 8388480

  size_t wsf = ws_size / 4;
  size_t partCap = (wsf > 1378304) ? wsf - 1378304 : 0;

  embed_kernel<<<dim3(BATCH), 256, 0, stream>>>(idx, emb_table, pos_table, x);

  int QC = (partCap >= (size_t)3 * 32 * BATCH * EMBD) ? 32 : 8;
  skgemm_qkv<<<dim3(4, QC, 3), 256, 0, stream>>>(x, Wk, Wv, Wq, part, EMBD / QC);
  reduce_qkv4<<<dim3(32, 3), 256, 0, stream>>>(part, QC, bk, bv, bq, k, v, q);

  attnA<<<dim3(NCH, BATCH), 256, 0, stream>>>(q, key_cache, k, value_cache, v, opart, ml);
  attnB<<<dim3(BATCH), 256, 0, stream>>>(opart, ml, attn);

  int F1C = (partCap >= (size_t)32 * BATCH * HIDD) ? 32 : 8;
  skgemm<BATCH><<<dim3(16, F1C), 256, 0, stream>>>(attn, W1, part, HIDD, EMBD, EMBD / F1C);
  reduce_ep4<<<dim3(128), 256, 0, stream>>>(part, F1C, b1, h, BATCH * HIDD / 4, HIDD - 1, 1);

  int F2C = (partCap >= (size_t)128 * BATCH * EMBD) ? 128 : 32;
  skgemm<BATCH><<<dim3(4, F2C), 256, 0, stream>>>(h, W2, part, EMBD, HIDD, HIDD / F2C);
  reduce_ep4<<<dim3(32), 256, 0, stream>>>(part, F2C, b2, ffn, BATCH * EMBD / 4, EMBD - 1, 0);

  if (partCap >= (size_t)4 * BATCH * VOC) {
    logits_v3<<<dim3(128, 4), 256, 0, stream>>>(ffn, Wl, part);
    logits_reduce4<<<dim3(2048), 256, 0, stream>>>(part, bl, out);
  } else {
    logits_splitb<<<dim3(256, 2), 256, 0, stream>>>(ffn, Wl, bl, out);
  }
}

// Round 5
// 240.603 us; speedup vs baseline: 1.4020x; 1.4020x over previous
//
#include <hip/hip_runtime.h>
#include <cstddef>

#define BATCH 32
#define EMBD 1024
#define SCTX 1023   // cached positions
#define CTXF 1024   // full context after concat
#define HIDD 4096
#define VOC 65535

// ---------------- embed: x[b] = emb[idx[b]] + pos[0] ----------------
__global__ void embed_kernel(const int* __restrict__ idx, const float* __restrict__ emb,
                             const float* __restrict__ pos, float* __restrict__ x) {
  int b = blockIdx.x, t = threadIdx.x;  // 32 blocks x 256
  const float4* er = (const float4*)(emb + (size_t)idx[b] * EMBD);
  const float4* pr = (const float4*)pos;
  float4 e = er[t], p = pr[t];
  ((float4*)(x + (size_t)b * EMBD))[t] = make_float4(e.x + p.x, e.y + p.y, e.z + p.z, e.w + p.w);
}

// ---------------- LDS-staged skinny GEMM (X broadcast from LDS) ----------------
// Block: 256 threads, one output column each. K-chunk of CHK staged transposed
// in LDS; inner loop: 1 coalesced weight load + broadcast LDS reads + 32 FMA.
template <int CHK>
__global__ __launch_bounds__(256) void skgemm_lds(const float* __restrict__ X,
                                                  const float* __restrict__ W,
                                                  float* __restrict__ Pout, int N, int K) {
  __shared__ float xt[CHK][BATCH];
  int t = threadIdx.x;
  int p = blockIdx.y;
  int i0 = p * CHK;
  for (int m = t; m < CHK * BATCH; m += 256) {
    int i = m >> 5, b = m & 31;
    xt[i][b] = X[b * K + i0 + i];
  }
  __syncthreads();

  int j = blockIdx.x * 256 + t;
  float acc[BATCH];
#pragma unroll
  for (int b = 0; b < BATCH; ++b) acc[b] = 0.f;
  const float* wp = W + (size_t)i0 * N + j;
#pragma unroll 8
  for (int i = 0; i < CHK; ++i) {
    float w = wp[(size_t)i * N];
#pragma unroll
    for (int b = 0; b < BATCH; ++b) acc[b] = fmaf(xt[i][b], w, acc[b]);
  }
#pragma unroll
  for (int b = 0; b < BATCH; ++b) Pout[((size_t)p * BATCH + b) * N + j] = acc[b];
}

// QKV: z selects weight; partial layout [z][p][b][j]
template <int CHK>
__global__ __launch_bounds__(256) void qkv_lds(const float* __restrict__ X,
                                               const float* __restrict__ Wk,
                                               const float* __restrict__ Wv,
                                               const float* __restrict__ Wq,
                                               float* __restrict__ Pout, int nch) {
  __shared__ float xt[CHK][BATCH];
  int t = threadIdx.x;
  int p = blockIdx.y;
  int i0 = p * CHK;
  for (int m = t; m < CHK * BATCH; m += 256) {
    int i = m >> 5, b = m & 31;
    xt[i][b] = X[b * EMBD + i0 + i];
  }
  __syncthreads();

  const float* __restrict__ W = (blockIdx.z == 0) ? Wk : (blockIdx.z == 1) ? Wv : Wq;
  int j = blockIdx.x * 256 + t;
  float acc[BATCH];
#pragma unroll
  for (int b = 0; b < BATCH; ++b) acc[b] = 0.f;
  const float* wp = W + (size_t)i0 * EMBD + j;
#pragma unroll 8
  for (int i = 0; i < CHK; ++i) {
    float w = wp[(size_t)i * EMBD];
#pragma unroll
    for (int b = 0; b < BATCH; ++b) acc[b] = fmaf(xt[i][b], w, acc[b]);
  }
#pragma unroll
  for (int b = 0; b < BATCH; ++b)
    Pout[((size_t)(blockIdx.z * nch + p) * BATCH + b) * EMBD + j] = acc[b];
}

__global__ void reduce_qkv(const float* __restrict__ part, int P,
                           const float* __restrict__ bk, const float* __restrict__ bv,
                           const float* __restrict__ bq,
                           float* __restrict__ kout, float* __restrict__ vout,
                           float* __restrict__ qout) {
  int z = blockIdx.y;
  int m = blockIdx.x * 256 + threadIdx.x;       // < 32768
  float s = 0.f;
  for (int p = 0; p < P; ++p) s += part[(size_t)(z * P + p) * (BATCH * EMBD) + m];
  const float* bias = (z == 0) ? bk : (z == 1) ? bv : bq;
  float* out = (z == 0) ? kout : (z == 1) ? vout : qout;
  out[m] = s + bias[m & (EMBD - 1)];
}

// out[m] = act( sum_p part[p][m] + bias[m & mask] )
__global__ void reduce_ep(const float* __restrict__ part, int P,
                          const float* __restrict__ bias, float* __restrict__ out,
                          int total, int mask, int act) {
  int m = blockIdx.x * 256 + threadIdx.x;
  if (m >= total) return;
  float s = 0.f;
  for (int p = 0; p < P; ++p) s += part[(size_t)p * total + m];
  if (bias) s += bias[m & mask];
  if (act == 1) s = 0.5f * s * (1.f + erff(s * 0.70710678118654752f));
  out[m] = s;
}

// ---------------- attention ----------------
// grid (64, 32): block = 4 waves, each wave computes 4 score rows concurrently
__global__ void scores_kernel(const float* __restrict__ q, const float* __restrict__ kcache,
                              const float* __restrict__ knew, float* __restrict__ scores) {
  int b = blockIdx.y;
  int wave = threadIdx.x >> 6, lane = threadIdx.x & 63;
  const float* qb = q + (size_t)b * EMBD;
  float4 qf[4];
#pragma unroll
  for (int r = 0; r < 4; ++r) qf[r] = *(const float4*)(qb + r * 256 + lane * 4);
  int sbase = blockIdx.x * 16 + wave * 4;
  const float* kr[4];
  float acc[4] = {0.f, 0.f, 0.f, 0.f};
#pragma unroll
  for (int it = 0; it < 4; ++it) {
    int s = sbase + it;
    kr[it] = (s < SCTX) ? (kcache + ((size_t)b * SCTX + s) * EMBD)
                        : (knew + (size_t)b * EMBD);
  }
#pragma unroll
  for (int r = 0; r < 4; ++r) {
#pragma unroll
    for (int it = 0; it < 4; ++it) {
      float4 kf = *(const float4*)(kr[it] + r * 256 + lane * 4);
      acc[it] += qf[r].x * kf.x + qf[r].y * kf.y + qf[r].z * kf.z + qf[r].w * kf.w;
    }
  }
#pragma unroll
  for (int it = 0; it < 4; ++it) {
    float a = acc[it];
#pragma unroll
    for (int m = 32; m > 0; m >>= 1) a += __shfl_xor(a, m, 64);
    if (lane == 0) scores[(size_t)b * CTXF + sbase + it] = a * 0.03125f;  // 1/sqrt(1024)
  }
}

__global__ void softmax_kernel(float* __restrict__ sc) {
  int b = blockIdx.x;
  int t = threadIdx.x;  // 1024
  __shared__ float red[16];
  float v = sc[(size_t)b * CTXF + t];
  float m = v;
#pragma unroll
  for (int d = 32; d > 0; d >>= 1) m = fmaxf(m, __shfl_xor(m, d, 64));
  if ((t & 63) == 0) red[t >> 6] = m;
  __syncthreads();
  float bm = red[0];
#pragma unroll
  for (int w = 1; w < 16; ++w) bm = fmaxf(bm, red[w]);
  float e = expf(v - bm);
  __syncthreads();
  float s = e;
#pragma unroll
  for (int d = 32; d > 0; d >>= 1) s += __shfl_xor(s, d, 64);
  if ((t & 63) == 0) red[t >> 6] = s;
  __syncthreads();
  float bs = 0.f;
#pragma unroll
  for (int w = 0; w < 16; ++w) bs += red[w];
  sc[(size_t)b * CTXF + t] = e / bs;
}

// grid (32, 32): 32 chunks of 32 rows
__global__ void pv_kernel(const float* __restrict__ probs, const float* __restrict__ vcache,
                          const float* __restrict__ vnew, float* __restrict__ part) {
  int b = blockIdx.y;
  int p = blockIdx.x;
  int t = threadIdx.x;  // 256
  float acc[4] = {0.f, 0.f, 0.f, 0.f};
  int s0 = p * 32;
#pragma unroll 4
  for (int s = s0; s < s0 + 32; ++s) {
    float pr = probs[(size_t)b * CTXF + s];
    const float* vrow = (s < SCTX) ? (vcache + ((size_t)b * SCTX + s) * EMBD)
                                   : (vnew + (size_t)b * EMBD);
#pragma unroll
    for (int r = 0; r < 4; ++r) acc[r] = fmaf(pr, vrow[t + r * 256], acc[r]);
  }
#pragma unroll
  for (int r = 0; r < 4; ++r) part[((size_t)p * BATCH + b) * EMBD + t + r * 256] = acc[r];
}

// ---------------- logits ----------------
// grid (128, 4), 256 threads. Block: 512 cols x 256-i K-chunk; X staged transposed in LDS.
__global__ __launch_bounds__(256) void logits_v3(const float* __restrict__ X,
                                                 const float* __restrict__ Wl,
                                                 float* __restrict__ part) {
  __shared__ float xt[256][BATCH];  // 32 KB
  int t = threadIdx.x;
  int p = blockIdx.y;
  int q0 = p * 256;
  for (int m = t; m < 256 * BATCH; m += 256) {
    int i = m >> 5, b = m & 31;
    xt[i][b] = X[b * EMBD + q0 + i];
  }
  __syncthreads();

  int jb = blockIdx.x * 512;
  int j0 = jb + t;
  int j1 = jb + 256 + t;
  bool v1 = (j1 < VOC);
  float acc0[BATCH], acc1[BATCH];
#pragma unroll
  for (int b = 0; b < BATCH; ++b) { acc0[b] = 0.f; acc1[b] = 0.f; }

  const float* wp = Wl + (size_t)q0 * VOC;
#pragma unroll 4
  for (int i = 0; i < 256; ++i) {
    float w0 = wp[(size_t)i * VOC + j0];
    float w1 = v1 ? wp[(size_t)i * VOC + j1] : 0.f;
#pragma unroll
    for (int b = 0; b < BATCH; ++b) {
      float xv = xt[i][b];
      acc0[b] = fmaf(xv, w0, acc0[b]);
      acc1[b] = fmaf(xv, w1, acc1[b]);
    }
  }
#pragma unroll
  for (int b = 0; b < BATCH; ++b) {
    part[((size_t)p * BATCH + b) * VOC + j0] = acc0[b];
    if (v1) part[((size_t)p * BATCH + b) * VOC + j1] = acc1[b];
  }
}

__global__ void logits_reduce(const float* __restrict__ part, const float* __restrict__ bl,
                              float* __restrict__ out) {
  size_t m = (size_t)blockIdx.x * 256 + threadIdx.x;
  if (m >= (size_t)BATCH * VOC) return;
  int j = (int)(m % VOC);
  float s = 0.f;
#pragma unroll
  for (int p = 0; p < 4; ++p) s += part[(size_t)p * BATCH * VOC + m];
  out[m] = s + bl[j];
}

// fallback (small ws): split batch in halves, full K, direct write
__global__ void logits_splitb(const float* __restrict__ X, const float* __restrict__ Wl,
                              const float* __restrict__ bl, float* __restrict__ out) {
  int j = blockIdx.x * 256 + threadIdx.x;
  if (j >= VOC) return;
  int b0 = blockIdx.y * 16;
  float acc[16];
#pragma unroll
  for (int b = 0; b < 16; ++b) acc[b] = 0.f;
#pragma unroll 8
  for (int i = 0; i < EMBD; ++i) {
    float w = Wl[(size_t)i * VOC + j];
#pragma unroll
    for (int b = 0; b < 16; ++b) acc[b] = fmaf(X[(b0 + b) * EMBD + i], w, acc[b]);
  }
  float bb = bl[j];
#pragma unroll
  for (int b = 0; b < 16; ++b) out[(size_t)(b0 + b) * VOC + j] = acc[b] + bb;
}

extern "C" void kernel_launch(void* const* d_in, const int* in_sizes, int n_in,
                              void* d_out, int out_size, void* d_ws, size_t ws_size,
                              hipStream_t stream) {
  const int* idx = (const int*)d_in[0];
  const float* key_cache = (const float*)d_in[1];
  const float* value_cache = (const float*)d_in[2];
  const float* emb_table = (const float*)d_in[3];
  const float* pos_table = (const float*)d_in[4];
  const float* Wk = (const float*)d_in[5];
  const float* bk = (const float*)d_in[6];
  const float* Wv = (const float*)d_in[7];
  const float* bv = (const float*)d_in[8];
  const float* Wq = (const float*)d_in[9];
  const float* bq = (const float*)d_in[10];
  const float* W1 = (const float*)d_in[11];
  const float* b1 = (const float*)d_in[12];
  const float* W2 = (const float*)d_in[13];
  const float* b2 = (const float*)d_in[14];
  const float* Wl = (const float*)d_in[15];
  const float* bl = (const float*)d_in[16];
  float* out = (float*)d_out;

  float* ws = (float*)d_ws;
  float* x    = ws;                    // 32768
  float* k    = ws + 32768;
  float* v    = ws + 65536;
  float* q    = ws + 98304;
  float* prob = ws + 131072;           // scores -> probs in place
  float* attn = ws + 163840;
  float* h    = ws + 196608;           // 131072
  float* ffn  = ws + 327680;
  float* part = ws + 360448;

  size_t partCap = (ws_size / 4 > 360448) ? ws_size / 4 - 360448 : 0;

  embed_kernel<<<dim3(BATCH), 256, 0, stream>>>(idx, emb_table, pos_table, x);

  // QKV: 32 chunks of 32 (384 blocks) if partials fit, else 8 chunks of 128
  if (partCap >= (size_t)3 * 32 * BATCH * EMBD) {
    qkv_lds<32><<<dim3(4, 32, 3), 256, 0, stream>>>(x, Wk, Wv, Wq, part, 32);
    reduce_qkv<<<dim3(128, 3), 256, 0, stream>>>(part, 32, bk, bv, bq, k, v, q);
  } else {
    qkv_lds<128><<<dim3(4, 8, 3), 256, 0, stream>>>(x, Wk, Wv, Wq, part, 8);
    reduce_qkv<<<dim3(128, 3), 256, 0, stream>>>(part, 8, bk, bv, bq, k, v, q);
  }

  scores_kernel<<<dim3(64, BATCH), 256, 0, stream>>>(q, key_cache, k, prob);
  softmax_kernel<<<dim3(BATCH), 1024, 0, stream>>>(prob);
  pv_kernel<<<dim3(32, BATCH), 256, 0, stream>>>(prob, value_cache, v, part);
  reduce_ep<<<dim3(128), 256, 0, stream>>>(part, 32, nullptr, attn, BATCH * EMBD, 0, 0);

  // FFN1: 16 chunks of 64 (grid 256)
  skgemm_lds<64><<<dim3(16, 16), 256, 0, stream>>>(attn, W1, part, HIDD, EMBD);
  reduce_ep<<<dim3(512), 256, 0, stream>>>(part, 16, b1, h, BATCH * HIDD, HIDD - 1, 1);

  // FFN2: 64 chunks of 64 (grid 256)
  skgemm_lds<64><<<dim3(4, 64), 256, 0, stream>>>(h, W2, part, EMBD, HIDD);
  reduce_ep<<<dim3(128), 256, 0, stream>>>(part, 64, b2, ffn, BATCH * EMBD, EMBD - 1, 0);

  if (partCap >= (size_t)4 * BATCH * VOC) {
    logits_v3<<<dim3(128, 4), 256, 0, stream>>>(ffn, Wl, part);
    logits_reduce<<<dim3(8192), 256, 0, stream>>>(part, bl, out);
  } else {
    logits_splitb<<<dim3(256, 2), 256, 0, stream>>>(ffn, Wl, bl, out);
  }
}